// Round 3
// baseline (734.448 us; speedup 1.0000x reference)
//
#include <hip/hip_runtime.h>

// WindowedNorm: 47x47 box-window mean/var normalization, zero-padded,
// count_include_pad=False, Bessel-corrected. NHWC fp32 [B,224,224,3].
//
// Fused single kernel, one (batch, 7-row band) per block.
//   Phase V: vertical 47-row window sums (S,Q) per owned column, computed
//            with branchless clamped+masked batched loads (8 rows in
//            flight); own-row x values stashed in registers; the 14
//            slide rows preloaded into registers. Publishes float2(S,Q)
//            per band row to LDS vsq[r*3+c][w].
//   Phase P: in-place inclusive prefix scan along w of the 21 (row,ch)
//            LDS rows; wave shfl_up scan, two rows interleaved per wave
//            to overlap the dependent shuffle chains.
//   Phase N: per-thread own columns x 7 rows (21 outputs, independent):
//            window = P[w+23]-P[w-24] (2 LDS b64 reads), normalize with
//            register-resident x, coalesced store. No global reads.

namespace {
constexpr int H = 224;
constexpr int W = 224;
constexpr int C = 3;
constexpr int WC = W * C;          // 672
constexpr int RAD = 23;            // window = 47
constexpr int TH = 7;              // rows per block (224/7 = 32 bands)
constexpr int PADW = W + 1;        // 225
constexpr int NROWS = TH * C;      // 21 scan rows
}

__global__ __launch_bounds__(256, 4) void wnorm_kernel(
    const float* __restrict__ in, float* __restrict__ out) {
  // 21 x 225 float2 = 37.8 KB -> 4 blocks/CU (16 waves/CU)
  __shared__ float2 vsq[NROWS][PADW];

  const int tid = threadIdx.x;
  const int lane = tid & 63;
  const int wv = tid >> 6;
  const int r0 = blockIdx.x * TH;
  const float* __restrict__ img = in + (size_t)blockIdx.y * (H * WC);
  float* __restrict__ oimg = out + (size_t)blockIdx.y * (H * WC);

  // thread owns cols tid, tid+256, tid+512 (last only if < 672)
  const int ncol = (tid < WC - 512) ? 3 : 2;
  int wk[3], ck[3];
#pragma unroll
  for (int k = 0; k < 3; ++k) {
    int col = tid + (k << 8);
    wk[k] = col / 3;
    ck[k] = col - 3 * wk[k];
  }

  // ---- own-row x values (kept in regs for Phase N; issued first) ----
  float xr[TH][3];
#pragma unroll
  for (int r = 0; r < TH; ++r)
#pragma unroll
    for (int k = 0; k < 3; ++k)
      if (k < ncol) xr[r][k] = img[(r0 + r) * WC + tid + (k << 8)];

  // ---- Phase V init: 47 rows, branchless clamped+masked, 8-row batches --
  float S[3] = {0.f, 0.f, 0.f};
  float Q[3] = {0.f, 0.f, 0.f};
  const int rlo = r0 - RAD;
  for (int i0 = 0; i0 < 48; i0 += 8) {   // 6 batches; position 47 masked
    float xb[8][3];
#pragma unroll
    for (int i = 0; i < 8; ++i) {
      const int r = rlo + i0 + i;
      const int rc = min(max(r, 0), H - 1);
      const float m = (r >= 0 && r < H && (i0 + i) < 47) ? 1.f : 0.f;
      const float* row = img + rc * WC;
#pragma unroll
      for (int k = 0; k < 3; ++k)
        if (k < ncol) xb[i][k] = row[tid + (k << 8)] * m;
    }
#pragma unroll
    for (int i = 0; i < 8; ++i)
#pragma unroll
      for (int k = 0; k < 3; ++k)
        if (k < ncol) { S[k] += xb[i][k]; Q[k] += xb[i][k] * xb[i][k]; }
  }

  // ---- preload the 14 slide rows (branchless) ----
  float xa[TH][3], xs[TH][3];
#pragma unroll
  for (int r = 0; r < TH; ++r) {
    const int ra = r0 + r + RAD + 1;           // row entering
    const int rca = min(ra, H - 1);
    const float ma = (ra < H) ? 1.f : 0.f;
    const int rs = r0 + r - RAD;               // row leaving
    const int rcs = max(rs, 0);
    const float ms = (rs >= 0) ? 1.f : 0.f;
#pragma unroll
    for (int k = 0; k < 3; ++k)
      if (k < ncol) {
        xa[r][k] = img[rca * WC + tid + (k << 8)] * ma;
        xs[r][k] = img[rcs * WC + tid + (k << 8)] * ms;
      }
  }

  // ---- steady: publish + slide (pure regs + LDS writes) ----
#pragma unroll
  for (int r = 0; r < TH; ++r) {
#pragma unroll
    for (int k = 0; k < 3; ++k)
      if (k < ncol) vsq[r * C + ck[k]][wk[k]] = make_float2(S[k], Q[k]);
#pragma unroll
    for (int k = 0; k < 3; ++k)
      if (k < ncol) {
        S[k] += xa[r][k]; Q[k] += xa[r][k] * xa[r][k];
        S[k] -= xs[r][k]; Q[k] -= xs[r][k] * xs[r][k];
      }
  }

  __syncthreads();

  // ---- Phase P: prefix scan along w, two rows interleaved per wave ----
  for (int rr = wv; rr < NROWS; rr += 8) {
    const int rA = rr;
    const int rB = rr + 4;
    const bool hasB = (rB < NROWS);
    float cAx = 0.f, cAy = 0.f, cBx = 0.f, cBy = 0.f;
#pragma unroll
    for (int chunk = 0; chunk < 4; ++chunk) {
      const int w = (chunk << 6) + lane;
      const bool act = (w < W);
      float2 vA = act ? vsq[rA][w] : make_float2(0.f, 0.f);
      float2 vB = (hasB && act) ? vsq[rB][w] : make_float2(0.f, 0.f);
#pragma unroll
      for (int d = 1; d < 64; d <<= 1) {
        float sAx = __shfl_up(vA.x, d), sAy = __shfl_up(vA.y, d);
        float sBx = __shfl_up(vB.x, d), sBy = __shfl_up(vB.y, d);
        if (lane >= d) {
          vA.x += sAx; vA.y += sAy;
          vB.x += sBx; vB.y += sBy;
        }
      }
      vA.x += cAx; vA.y += cAy;
      vB.x += cBx; vB.y += cBy;
      if (act) vsq[rA][w] = vA;
      if (hasB && act) vsq[rB][w] = vB;
      cAx = __shfl(vA.x, 63); cAy = __shfl(vA.y, 63);
      cBx = __shfl(vB.x, 63); cBy = __shfl(vB.y, 63);
    }
  }

  __syncthreads();

  // ---- Phase N: normalize own columns x 7 rows, coalesced store ----
#pragma unroll
  for (int r = 0; r < TH; ++r) {
    const int h = r0 + r;
    const float chh = (float)(min(h + RAD, H - 1) - max(h - RAD, 0) + 1);
#pragma unroll
    for (int k = 0; k < 3; ++k)
      if (k < ncol) {
        const int w = wk[k], c = ck[k];
        const int hiw = min(w + RAD, W - 1);
        const int low = w - RAD - 1;
        const float2 Ph = vsq[r * C + c][hiw];
        const float2 Pl = (low >= 0) ? vsq[r * C + c][low]
                                     : make_float2(0.f, 0.f);
        const float HS = Ph.x - Pl.x;
        const float HQ = Ph.y - Pl.y;
        const float n = chh * (float)(hiw - max(w - RAD, 0) + 1);
        const float inv = 1.0f / n;
        const float mean = HS * inv;
        float var = (HQ * inv - mean * mean) * (n / (n - 1.0f));
        var = fmaxf(var, 0.0f);
        oimg[h * WC + tid + (k << 8)] =
            (xr[r][k] - mean) * rsqrtf(var + 1e-6f);
      }
  }
}

extern "C" void kernel_launch(void* const* d_in, const int* in_sizes, int n_in,
                              void* d_out, int out_size, void* d_ws, size_t ws_size,
                              hipStream_t stream) {
  const float* in = (const float*)d_in[0];
  float* out = (float*)d_out;
  const int B = in_sizes[0] / (H * W * C);   // 128
  dim3 grid(H / TH, B);                      // 32 x 128
  wnorm_kernel<<<grid, 256, 0, stream>>>(in, out);
}

// Round 4
// 215.712 us; speedup vs baseline: 3.4048x; 3.4048x over previous
//
#include <hip/hip_runtime.h>

// WindowedNorm: 47x47 box-window mean/var normalization, zero-padded,
// count_include_pad=False, Bessel-corrected. NHWC fp32 [B,224,224,3].
//
// Fused single kernel, one (batch, 7-row band) per block.
// Thread t (t<224) owns pixel-column w=t, ALL 3 channels (contiguous in
// NHWC -> dwordx3 loads/stores).
//   Phase V: vertical 47-row running window sums (S,Q) per channel,
//            6 scalar accumulators, one float3 load per row. Publishes
//            float2(S,Q) to LDS vsq[r*3+c][w] per band row.
//   Phase P: per (row,ch) LDS row: single-wave two-level inclusive scan
//            (lane owns 4 consecutive w; 2 b128 reads, 6-level shfl scan
//            of lane totals, 2 b128 writes). No inter-chunk carry.
//   Phase N: window sum = P[w+23]-P[w-24]; count math hoisted per row
//            (shared across channels); dwordx3 x re-read + dwordx3 store.

namespace {
constexpr int H = 224;
constexpr int W = 224;
constexpr int C = 3;
constexpr int WC = W * C;          // 672
constexpr int RAD = 23;            // window = 47
constexpr int TH = 7;              // rows per block (224/7 = 32 bands)
constexpr int PADW = 226;          // float2/row; 226*8=1808B, 16B-aligned
constexpr int NROWS = TH * C;      // 21 scan rows
}

__global__ __launch_bounds__(256, 4) void wnorm_kernel(
    const float* __restrict__ in, float* __restrict__ out) {
  // 21 x 226 float2 = 37.97 KB -> 4 blocks/CU (16 waves/CU)
  __shared__ float2 vsq[NROWS][PADW];

  const int tid = threadIdx.x;
  const int lane = tid & 63;
  const int wv = tid >> 6;
  const int r0 = blockIdx.x * TH;
  const float* __restrict__ img = in + (size_t)blockIdx.y * (H * WC);
  float* __restrict__ oimg = out + (size_t)blockIdx.y * (H * WC);

  const bool own = (tid < W);
  const int w = tid;

  // ---- Phase V ----
  float S0 = 0.f, S1 = 0.f, S2 = 0.f, Q0 = 0.f, Q1 = 0.f, Q2 = 0.f;
  if (own) {
    const int rlo = r0 - RAD;
#pragma unroll 4
    for (int i = 0; i < 47; ++i) {
      const int r = rlo + i;
      const int rc = min(max(r, 0), H - 1);
      const float m = (r >= 0 && r < H) ? 1.f : 0.f;
      const float3 v = ((const float3*)(img + rc * WC))[w];
      const float x0 = v.x * m, x1 = v.y * m, x2 = v.z * m;
      S0 += x0; Q0 += x0 * x0;
      S1 += x1; Q1 += x1 * x1;
      S2 += x2; Q2 += x2 * x2;
    }
  }

#pragma unroll
  for (int r = 0; r < TH; ++r) {
    if (own) {
      vsq[r * C + 0][w] = make_float2(S0, Q0);
      vsq[r * C + 1][w] = make_float2(S1, Q1);
      vsq[r * C + 2][w] = make_float2(S2, Q2);
    }
    const int ra = r0 + r + RAD + 1;   // row entering (block-uniform cond)
    const int rs = r0 + r - RAD;       // row leaving  (block-uniform cond)
    if (ra < H && own) {
      const float3 v = ((const float3*)(img + ra * WC))[w];
      S0 += v.x; Q0 += v.x * v.x;
      S1 += v.y; Q1 += v.y * v.y;
      S2 += v.z; Q2 += v.z * v.z;
    }
    if (rs >= 0 && own) {
      const float3 v = ((const float3*)(img + rs * WC))[w];
      S0 -= v.x; Q0 -= v.x * v.x;
      S1 -= v.y; Q1 -= v.y * v.y;
      S2 -= v.z; Q2 -= v.z * v.z;
    }
  }

  __syncthreads();

  // ---- Phase P: one wave per (row,ch) LDS row, lane owns 4 consecutive w
  for (int rr = wv; rr < NROWS; rr += 4) {
    const bool act = (lane < 56);          // 56 lanes x 4 = 224
    const int w0 = lane << 2;
    float4* p4 = reinterpret_cast<float4*>(&vsq[rr][act ? w0 : 0]);
    float4 a = make_float4(0.f, 0.f, 0.f, 0.f), b = a;
    if (act) { a = p4[0]; b = p4[1]; }
    // lane-local inclusive partials (float2 elems: (x,y)=(S,Q))
    const float p0x = a.x,        p0y = a.y;
    const float p1x = p0x + a.z,  p1y = p0y + a.w;
    const float p2x = p1x + b.x,  p2y = p1y + b.y;
    const float p3x = p2x + b.z,  p3y = p2y + b.w;
    // wave-inclusive scan of lane totals
    float Tx = p3x, Ty = p3y;
#pragma unroll
    for (int d = 1; d < 64; d <<= 1) {
      const float sx = __shfl_up(Tx, d);
      const float sy = __shfl_up(Ty, d);
      if (lane >= d) { Tx += sx; Ty += sy; }
    }
    const float ex = Tx - p3x, ey = Ty - p3y;   // exclusive-before-lane
    if (act) {
      p4[0] = make_float4(p0x + ex, p0y + ey, p1x + ex, p1y + ey);
      p4[1] = make_float4(p2x + ex, p2y + ey, p3x + ex, p3y + ey);
    }
  }

  __syncthreads();

  // ---- Phase N ----
  if (own) {
    const int hiw = min(w + RAD, W - 1);
    const int low = w - RAD - 1;               // exclusive left, may be <0
    const float cww = (float)(hiw - max(w - RAD, 0) + 1);
#pragma unroll
    for (int r = 0; r < TH; ++r) {
      const int h = r0 + r;
      const float chh =
          (float)(min(h + RAD, H - 1) - max(h - RAD, 0) + 1);
      const float n = chh * cww;
      const float inv = 1.0f / n;
      const float bes = n / (n - 1.0f);
      const float3 x = ((const float3*)(img + h * WC))[w];
      float o[3];
      const float xc[3] = {x.x, x.y, x.z};
#pragma unroll
      for (int c = 0; c < C; ++c) {
        const float2 Ph = vsq[r * C + c][hiw];
        const float2 Pl = (low >= 0) ? vsq[r * C + c][low]
                                     : make_float2(0.f, 0.f);
        const float mean = (Ph.x - Pl.x) * inv;
        float var = ((Ph.y - Pl.y) * inv - mean * mean) * bes;
        var = fmaxf(var, 0.0f);
        o[c] = (xc[c] - mean) * rsqrtf(var + 1e-6f);
      }
      ((float3*)(oimg + h * WC))[w] = make_float3(o[0], o[1], o[2]);
    }
  }
}

extern "C" void kernel_launch(void* const* d_in, const int* in_sizes, int n_in,
                              void* d_out, int out_size, void* d_ws, size_t ws_size,
                              hipStream_t stream) {
  const float* in = (const float*)d_in[0];
  float* out = (float*)d_out;
  const int B = in_sizes[0] / (H * W * C);   // 128
  dim3 grid(H / TH, B);                      // 32 x 128
  wnorm_kernel<<<grid, 256, 0, stream>>>(in, out);
}

// Round 6
// 179.876 us; speedup vs baseline: 4.0831x; 1.1992x over previous
//
#include <hip/hip_runtime.h>

// WindowedNorm: 47x47 box-window mean/var normalization, zero-padded,
// count_include_pad=False, Bessel-corrected. NHWC fp32 [B,224,224,3].
//
// One (batch, 28-row band) per block, processed as 4 sequential 7-row
// sub-bands that reuse one 38KB LDS buffer (4 blocks/CU). Vertical
// running sums persist in registers across sub-bands, so the 47-row
// init amortizes 4x better than a 7-row band (requested dwords/output
// 9.7 -> 4.7).
// Thread t (t<224) owns pixel-column w=t, all 3 channels (float3 ops).
//   Phase V (per sub-band): publish float2(S,Q) to vsq[r*3+c][w] for the
//            7 rows, stash own-row x in 21 statically-indexed registers,
//            slide the 47-row window (add h+24 / sub h-23, float3 loads).
//   Phase P: per (row,ch) LDS row: single-wave two-level inclusive scan
//            (lane owns 4 consecutive w; 2 b128 reads, 6-level shfl scan,
//            2 b128 writes).
//   Phase N: window sum = P[w+23]-P[w-24]; per-row count math hoisted;
//            normalize register-stashed x; float3 coalesced store.

namespace {
constexpr int H = 224;
constexpr int W = 224;
constexpr int C = 3;
constexpr int WC = W * C;          // 672
constexpr int RAD = 23;            // window = 47
constexpr int SB = 7;              // rows per sub-band
constexpr int NSB = 4;             // sub-bands per block
constexpr int TH = SB * NSB;       // 28 rows per block (grid.x = 8)
constexpr int PADW = 226;          // float2/row; 226*8=1808B (16B mult.)
constexpr int NROWS = SB * C;      // 21 scan rows
}

__global__ __launch_bounds__(256, 4) void wnorm_kernel(
    const float* __restrict__ in, float* __restrict__ out) {
  // 21 x 226 float2 = 37.97 KB -> 4 blocks/CU (16 waves/CU)
  __shared__ float2 vsq[NROWS][PADW];

  const int tid = threadIdx.x;
  const int lane = tid & 63;
  const int wv = tid >> 6;
  const int r0 = blockIdx.x * TH;
  const float* __restrict__ img = in + (size_t)blockIdx.y * (H * WC);
  float* __restrict__ oimg = out + (size_t)blockIdx.y * (H * WC);

  const bool own = (tid < W);
  const int w = tid;

  // ---- 47-row window init (once per 28 output rows) ----
  float S0 = 0.f, S1 = 0.f, S2 = 0.f, Q0 = 0.f, Q1 = 0.f, Q2 = 0.f;
  if (own) {
    const int rlo = r0 - RAD;
#pragma unroll 8
    for (int i = 0; i < 47; ++i) {
      const int r = rlo + i;
      const int rc = min(max(r, 0), H - 1);
      const float m = (r >= 0 && r < H) ? 1.f : 0.f;
      const float3 v = ((const float3*)(img + rc * WC))[w];
      const float x0 = v.x * m, x1 = v.y * m, x2 = v.z * m;
      S0 += x0; Q0 += x0 * x0;
      S1 += x1; Q1 += x1 * x1;
      S2 += x2; Q2 += x2 * x2;
    }
  }

  // per-thread horizontal window geometry (invariant across rows)
  const int hiw = min(w + RAD, W - 1);
  const int low = w - RAD - 1;               // exclusive left, may be <0
  const float cww = (float)(hiw - max(w - RAD, 0) + 1);

  float xr0[SB], xr1[SB], xr2[SB];           // own-row x stash (static idx)

  for (int sb = 0; sb < NSB; ++sb) {
    const int hb = r0 + sb * SB;

    // ---- Phase V: publish + x-stash + slide ----
#pragma unroll
    for (int r = 0; r < SB; ++r) {
      const int h = hb + r;
      if (own) {
        vsq[r * C + 0][w] = make_float2(S0, Q0);
        vsq[r * C + 1][w] = make_float2(S1, Q1);
        vsq[r * C + 2][w] = make_float2(S2, Q2);
        const float3 xv = ((const float3*)(img + h * WC))[w];
        xr0[r] = xv.x; xr1[r] = xv.y; xr2[r] = xv.z;
      }
      const int ra = h + RAD + 1;            // row entering
      const int rs = h - RAD;                // row leaving
      if (ra < H && own) {
        const float3 v = ((const float3*)(img + ra * WC))[w];
        S0 += v.x; Q0 += v.x * v.x;
        S1 += v.y; Q1 += v.y * v.y;
        S2 += v.z; Q2 += v.z * v.z;
      }
      if (rs >= 0 && own) {
        const float3 v = ((const float3*)(img + rs * WC))[w];
        S0 -= v.x; Q0 -= v.x * v.x;
        S1 -= v.y; Q1 -= v.y * v.y;
        S2 -= v.z; Q2 -= v.z * v.z;
      }
    }

    __syncthreads();

    // ---- Phase P: one wave per (row,ch) LDS row ----
    for (int rr = wv; rr < NROWS; rr += 4) {
      const bool act = (lane < 56);          // 56 lanes x 4 = 224
      const int w0 = lane << 2;
      float4* p4 = reinterpret_cast<float4*>(&vsq[rr][act ? w0 : 0]);
      float4 a = make_float4(0.f, 0.f, 0.f, 0.f), b = a;
      if (act) { a = p4[0]; b = p4[1]; }
      const float p0x = a.x,       p0y = a.y;
      const float p1x = p0x + a.z, p1y = p0y + a.w;
      const float p2x = p1x + b.x, p2y = p1y + b.y;
      const float p3x = p2x + b.z, p3y = p2y + b.w;
      float Tx = p3x, Ty = p3y;
#pragma unroll
      for (int d = 1; d < 64; d <<= 1) {
        const float sx = __shfl_up(Tx, d);
        const float sy = __shfl_up(Ty, d);
        if (lane >= d) { Tx += sx; Ty += sy; }
      }
      const float ex = Tx - p3x, ey = Ty - p3y;  // exclusive-before-lane
      if (act) {
        p4[0] = make_float4(p0x + ex, p0y + ey, p1x + ex, p1y + ey);
        p4[1] = make_float4(p2x + ex, p2y + ey, p3x + ex, p3y + ey);
      }
    }

    __syncthreads();

    // ---- Phase N: normalize + coalesced store ----
    if (own) {
#pragma unroll
      for (int r = 0; r < SB; ++r) {
        const int h = hb + r;
        const float chh =
            (float)(min(h + RAD, H - 1) - max(h - RAD, 0) + 1);
        const float n = chh * cww;
        const float inv = 1.0f / n;
        const float bes = n / (n - 1.0f);
        const float xc[3] = {xr0[r], xr1[r], xr2[r]};
        float o[3];
#pragma unroll
        for (int c = 0; c < C; ++c) {
          const float2 Ph = vsq[r * C + c][hiw];
          const float2 Pl = (low >= 0) ? vsq[r * C + c][low]
                                       : make_float2(0.f, 0.f);
          const float mean = (Ph.x - Pl.x) * inv;
          float var = ((Ph.y - Pl.y) * inv - mean * mean) * bes;
          var = fmaxf(var, 0.0f);
          o[c] = (xc[c] - mean) * rsqrtf(var + 1e-6f);
        }
        ((float3*)(oimg + h * WC))[w] = make_float3(o[0], o[1], o[2]);
      }
    }

    __syncthreads();   // protect vsq before next sub-band's publish
  }
}

extern "C" void kernel_launch(void* const* d_in, const int* in_sizes, int n_in,
                              void* d_out, int out_size, void* d_ws, size_t ws_size,
                              hipStream_t stream) {
  const float* in = (const float*)d_in[0];
  float* out = (float*)d_out;
  const int B = in_sizes[0] / (H * W * C);   // 128
  dim3 grid(H / TH, B);                      // 8 x 128 = 1024 blocks
  wnorm_kernel<<<grid, 256, 0, stream>>>(in, out);
}

// Round 7
// 179.157 us; speedup vs baseline: 4.0995x; 1.0040x over previous
//
#include <hip/hip_runtime.h>

// WindowedNorm: 47x47 box-window mean/var normalization, zero-padded,
// count_include_pad=False, Bessel-corrected. NHWC fp32 [B,224,224,3].
//
// One (batch, 16-row band) per block, processed as 4 sequential 4-row
// sub-bands reusing one 21.7KB LDS buffer -> 7 blocks/CU (28 waves/CU).
// Vertical running sums persist in registers across sub-bands (47-row
// init paid once per 16 output rows).
// Thread t (t<224) owns pixel-column w=t, all 3 channels (float3 ops).
//   Phase V (per sub-band): publish float2(S,Q) to vsq[r*3+c][w] for 4
//            rows, stash own-row x in 12 statically-indexed registers,
//            slide the 47-row window (add h+24 / sub h-23, float3 loads).
//   Phase P: 12 scan rows / 4 waves = exactly 3 per wave (balanced);
//            per row: lane owns 4 consecutive w; 2 b128 reads, 6-level
//            shfl scan of lane totals, 2 b128 writes.
//   Phase N: window sum = P[w+23]-P[w-24]; per-row count math hoisted;
//            normalize register-stashed x; float3 coalesced store.

namespace {
constexpr int H = 224;
constexpr int W = 224;
constexpr int C = 3;
constexpr int WC = W * C;          // 672
constexpr int RAD = 23;            // window = 47
constexpr int SB = 4;              // rows per sub-band
constexpr int NSB = 4;             // sub-bands per block
constexpr int TH = SB * NSB;       // 16 rows per block (grid.x = 14)
constexpr int PADW = 226;          // float2/row; 226*8=1808B (16B mult.)
constexpr int NROWS = SB * C;      // 12 scan rows -> 21,696 B LDS
}

__global__ __launch_bounds__(256, 7) void wnorm_kernel(
    const float* __restrict__ in, float* __restrict__ out) {
  // 12 x 226 float2 = 21.7 KB -> 7 blocks/CU (28 waves/CU)
  __shared__ float2 vsq[NROWS][PADW];

  const int tid = threadIdx.x;
  const int lane = tid & 63;
  const int wv = tid >> 6;
  const int r0 = blockIdx.x * TH;
  const float* __restrict__ img = in + (size_t)blockIdx.y * (H * WC);
  float* __restrict__ oimg = out + (size_t)blockIdx.y * (H * WC);

  const bool own = (tid < W);
  const int w = tid;

  // ---- 47-row window init (once per 16 output rows) ----
  float S0 = 0.f, S1 = 0.f, S2 = 0.f, Q0 = 0.f, Q1 = 0.f, Q2 = 0.f;
  if (own) {
    const int rlo = r0 - RAD;
#pragma unroll 8
    for (int i = 0; i < 47; ++i) {
      const int r = rlo + i;
      const int rc = min(max(r, 0), H - 1);
      const float m = (r >= 0 && r < H) ? 1.f : 0.f;
      const float3 v = ((const float3*)(img + rc * WC))[w];
      const float x0 = v.x * m, x1 = v.y * m, x2 = v.z * m;
      S0 += x0; Q0 += x0 * x0;
      S1 += x1; Q1 += x1 * x1;
      S2 += x2; Q2 += x2 * x2;
    }
  }

  // per-thread horizontal window geometry (invariant across rows)
  const int hiw = min(w + RAD, W - 1);
  const int low = w - RAD - 1;               // exclusive left, may be <0
  const float cww = (float)(hiw - max(w - RAD, 0) + 1);

  float xr0[SB], xr1[SB], xr2[SB];           // own-row x stash (static idx)

  for (int sb = 0; sb < NSB; ++sb) {
    const int hb = r0 + sb * SB;

    // ---- Phase V: publish + x-stash + slide ----
#pragma unroll
    for (int r = 0; r < SB; ++r) {
      const int h = hb + r;
      if (own) {
        vsq[r * C + 0][w] = make_float2(S0, Q0);
        vsq[r * C + 1][w] = make_float2(S1, Q1);
        vsq[r * C + 2][w] = make_float2(S2, Q2);
        const float3 xv = ((const float3*)(img + h * WC))[w];
        xr0[r] = xv.x; xr1[r] = xv.y; xr2[r] = xv.z;
      }
      const int ra = h + RAD + 1;            // row entering
      const int rs = h - RAD;                // row leaving
      if (ra < H && own) {
        const float3 v = ((const float3*)(img + ra * WC))[w];
        S0 += v.x; Q0 += v.x * v.x;
        S1 += v.y; Q1 += v.y * v.y;
        S2 += v.z; Q2 += v.z * v.z;
      }
      if (rs >= 0 && own) {
        const float3 v = ((const float3*)(img + rs * WC))[w];
        S0 -= v.x; Q0 -= v.x * v.x;
        S1 -= v.y; Q1 -= v.y * v.y;
        S2 -= v.z; Q2 -= v.z * v.z;
      }
    }

    __syncthreads();

    // ---- Phase P: 3 scan rows per wave (balanced) ----
#pragma unroll
    for (int rr = wv; rr < NROWS; rr += 4) {
      const bool act = (lane < 56);          // 56 lanes x 4 = 224
      const int w0 = lane << 2;
      float4* p4 = reinterpret_cast<float4*>(&vsq[rr][act ? w0 : 0]);
      float4 a = make_float4(0.f, 0.f, 0.f, 0.f), b = a;
      if (act) { a = p4[0]; b = p4[1]; }
      const float p0x = a.x,       p0y = a.y;
      const float p1x = p0x + a.z, p1y = p0y + a.w;
      const float p2x = p1x + b.x, p2y = p1y + b.y;
      const float p3x = p2x + b.z, p3y = p2y + b.w;
      float Tx = p3x, Ty = p3y;
#pragma unroll
      for (int d = 1; d < 64; d <<= 1) {
        const float sx = __shfl_up(Tx, d);
        const float sy = __shfl_up(Ty, d);
        if (lane >= d) { Tx += sx; Ty += sy; }
      }
      const float ex = Tx - p3x, ey = Ty - p3y;  // exclusive-before-lane
      if (act) {
        p4[0] = make_float4(p0x + ex, p0y + ey, p1x + ex, p1y + ey);
        p4[1] = make_float4(p2x + ex, p2y + ey, p3x + ex, p3y + ey);
      }
    }

    __syncthreads();

    // ---- Phase N: normalize + coalesced store ----
    if (own) {
#pragma unroll
      for (int r = 0; r < SB; ++r) {
        const int h = hb + r;
        const float chh =
            (float)(min(h + RAD, H - 1) - max(h - RAD, 0) + 1);
        const float n = chh * cww;
        const float inv = 1.0f / n;
        const float bes = n / (n - 1.0f);
        const float xc[3] = {xr0[r], xr1[r], xr2[r]};
        float o[3];
#pragma unroll
        for (int c = 0; c < C; ++c) {
          const float2 Ph = vsq[r * C + c][hiw];
          const float2 Pl = (low >= 0) ? vsq[r * C + c][low]
                                       : make_float2(0.f, 0.f);
          const float mean = (Ph.x - Pl.x) * inv;
          float var = ((Ph.y - Pl.y) * inv - mean * mean) * bes;
          var = fmaxf(var, 0.0f);
          o[c] = (xc[c] - mean) * rsqrtf(var + 1e-6f);
        }
        ((float3*)(oimg + h * WC))[w] = make_float3(o[0], o[1], o[2]);
      }
    }

    __syncthreads();   // protect vsq before next sub-band's publish
  }
}

extern "C" void kernel_launch(void* const* d_in, const int* in_sizes, int n_in,
                              void* d_out, int out_size, void* d_ws, size_t ws_size,
                              hipStream_t stream) {
  const float* in = (const float*)d_in[0];
  float* out = (float*)d_out;
  const int B = in_sizes[0] / (H * W * C);   // 128
  dim3 grid(H / TH, B);                      // 14 x 128 = 1792 blocks
  wnorm_kernel<<<grid, 256, 0, stream>>>(in, out);
}